// Round 4
// baseline (227.410 us; speedup 1.0000x reference)
//
#include <hip/hip_runtime.h>
#include <hip/hip_bf16.h>
#include <stdint.h>

typedef __attribute__((ext_vector_type(8))) short bf16x8;  // 8 bf16 (4 VGPRs)
typedef __attribute__((ext_vector_type(4))) float f32x4;   // 4 f32 acc

#define RD 1024
#define LD 112
#define SCALE_C 2.8853900817779268f   // 2/ln2: tanh(z) = 1 - 2/(1+2^(C*z))
#define CHK 64                        // k per LDS chunk in fence_out
#define NCHK (RD/CHK)                 // 16 chunks
#define NB_CONV 6144                  // (400*1024 + 1024*1024 + 112*1024)/256

static __device__ __forceinline__ unsigned pkbf(float lo, float hi){
  return __builtin_amdgcn_perm(__builtin_bit_cast(unsigned, hi),
                               __builtin_bit_cast(unsigned, lo), 0x07060302u);
}
static __device__ __forceinline__ float exp2_f(float t){
#if __has_builtin(__builtin_amdgcn_exp2f)
  return __builtin_amdgcn_exp2f(t);
#else
  return exp2f(t);
#endif
}
static __device__ __forceinline__ float rcp_f(float t){
#if __has_builtin(__builtin_amdgcn_rcpf)
  return __builtin_amdgcn_rcpf(t);
#else
  return 1.0f / t;
#endif
}
static __device__ __forceinline__ short f2bf_rn(float f){
  unsigned u = __builtin_bit_cast(unsigned, f);
  return (short)((u + 0x7fffu + ((u >> 16) & 1u)) >> 16);
}
typedef const __attribute__((address_space(1))) unsigned int* gas1;
typedef __attribute__((address_space(3))) unsigned int* las3;
static __device__ __forceinline__ void g2lds16(const void* g, void* l){
  __builtin_amdgcn_global_load_lds((gas1)g, (las3)l, 16, 0, 0);
}

// ---- fused prep: bf16 conversions + SB[l] = sum_r P[r][l] + out_bias[l] ----
__global__ void fence_prep(const float* __restrict__ x, const float* __restrict__ W,
                           const float* __restrict__ P, const float* __restrict__ ob,
                           short* __restrict__ fpb, short* __restrict__ Wb,
                           short* __restrict__ Pt2, float* __restrict__ SB, int ntok){
  __shared__ float red[256];
  int blk = blockIdx.x, t = threadIdx.x;
  if (blk < NB_CONV){
    int id = blk*256 + t;
    int nfp = ntok * RD;
    if (id < nfp){
      int tok = id >> 10, d = id & (RD - 1);
      float v = 0.0f;
      if (tok < ntok - 1) v = (d < RD/2) ? x[tok*RD + d] : -x[(tok+1)*RD + d];
      fpb[id] = f2bf_rn(v);
    } else if (id < nfp + RD*RD){
      int p = id - nfp;
      Wb[p] = f2bf_rn(W[p]);
    } else {
      int p = id - nfp - RD*RD;   // < LD*RD by exact grid sizing
      int l = p >> 10, r = p & (RD - 1);
      Pt2[p] = f2bf_rn(-2.0f * P[r*LD + l]);
    }
  } else {
    int l = blk - NB_CONV;        // 0..LD-1
    float s = 0.0f;
    for (int r = t; r < RD; r += 256) s += P[r*LD + l];
    red[t] = s; __syncthreads();
    for (int st = 128; st > 0; st >>= 1){
      if (t < st) red[t] += red[t + st];
      __syncthreads();
    }
    if (t == 0) SB[l] = red[0] + ob[l];
  }
}

// ---- fence_y: y = fp*W^T (bf16 MFMA); epilogue E=2^(C(y+b)), F=2^(-Cy) ----
__global__ __launch_bounds__(256, 4)
void fence_y(const short* __restrict__ fpb, const short* __restrict__ Wb,
             const float* __restrict__ b, float* __restrict__ E,
             float* __restrict__ F, int ntok){
  int wid  = blockIdx.x * 4 + (threadIdx.x >> 6);
  int lane = threadIdx.x & 63;
  int mt = wid >> 6;          // 0..24
  int ng = wid & 63;          // 0..63
  int lm = lane & 15, rq = lane >> 4;
  int arow = mt*16 + lm; if (arow > ntok - 1) arow = ntok - 1;
  const short* Ap = fpb + (size_t)arow*RD + rq*8;
  const short* Bp = Wb + (size_t)(ng*16 + lm)*RD + rq*8;
  f32x4 acc = {};
  #pragma unroll
  for (int kb = 0; kb < 32; ++kb){
    bf16x8 a = *(const bf16x8*)(Ap + kb*32);
    bf16x8 w = *(const bf16x8*)(Bp + kb*32);
    acc = __builtin_amdgcn_mfma_f32_16x16x32_bf16(a, w, acc, 0, 0, 0);
  }
  int r = ng*16 + lm;
  float bv = b[r];
  #pragma unroll
  for (int reg = 0; reg < 4; ++reg){
    int t = mt*16 + rq*4 + reg;
    if (t < ntok){
      float y = acc[reg];
      E[(size_t)t*RD + r] = exp2_f(SCALE_C * (y + bv));
      F[(size_t)t*RD + r] = exp2_f(-SCALE_C * y);
    }
  }
}

// ---- fence_out: out[i,j,l] = SB[l] - 2*sum_r sigma*P[r,l], sigma=1/(1+E_j F_i).
//      R0 geometry restored (8i x 16j block, 4 waves x 2 i-rows, VGPR~60,
//      acc 56 AGPR, double-buffered LDS): R1-R3 proved every variant that
//      crossed a resource threshold (>128 total regs or >40KB LDS) halved
//      resident waves and regressed. R4 change: E and F are no longer LDS-
//      staged -- they are small L2-resident arrays with register-friendly
//      per-lane row access, so read them directly from global at the use
//      site. LDS now holds only Pt2 (2 x 14KB): LDS-pipe reads per
//      wave-chunk drop 26 -> 14 (the dominant pipe, ~34us -> ~18us) at ZERO
//      occupancy cost, and the per-chunk stage queue shrinks 20 -> 14 loads
//      (shorter barrier drain). ----
__global__ __launch_bounds__(256, 4)
void fence_out(const float* __restrict__ E, const float* __restrict__ F,
               const short* __restrict__ Pt2, const float* __restrict__ SB,
               float* __restrict__ out, int nn, int njt){
  __shared__ __align__(16) char sbuf[2][14336];
  int wave = threadIdx.x >> 6, lane = threadIdx.x & 63;
  int lm = lane & 15, rq = lane >> 4;
  int it = blockIdx.x / njt, jt = blockIdx.x - it*njt;
  int ibase = it*8, jbase = jt*16;

  // Pt2 stage descriptors: 14 x 1KB blocks over 4 waves (waves 0-1: 4, 2-3: 3)
  const char* gp[4]; int lof[4]; bool act[4];
  #pragma unroll
  for (int s = 0; s < 4; ++s){
    int q = wave + s*4;
    act[s] = (q < 14);
    int qq = act[s] ? q : 0;
    int kb = qq / 7, g = qq - kb*7;
    gp[s]  = (const char*)(Pt2 + (size_t)(g*16 + lm)*RD + kb*32 + rq*8);
    lof[s] = qq*1024;
  }
  auto stage = [&](int c, int bi){
    #pragma unroll
    for (int s = 0; s < 4; ++s)
      if (act[s]) g2lds16(gp[s] + (size_t)c*(CHK*2), &sbuf[bi][lof[s]]);
  };

  // direct-from-L2 row pointers: E per-lane j-row, F per-wave i-rows
  int jr = jbase + lm; if (jr > nn - 1) jr = nn - 1;
  const float* Ep = E + (size_t)jr*RD + rq*8;
  int ir0 = ibase + wave*2;     if (ir0 > nn - 1) ir0 = nn - 1;
  int ir1 = ibase + wave*2 + 1; if (ir1 > nn - 1) ir1 = nn - 1;
  const float* Fp0 = F + (size_t)ir0*RD + rq*8;
  const float* Fp1 = F + (size_t)ir1*RD + rq*8;

  stage(0, 0);

  f32x4 acc[2][7];
  #pragma unroll
  for (int nt = 0; nt < 7; ++nt){
    float sv = SB[nt*16 + lm];
    acc[0][nt] = (f32x4){sv, sv, sv, sv};
    acc[1][nt] = (f32x4){sv, sv, sv, sv};
  }
  __syncthreads();

  for (int c = 0; c < NCHK; ++c){
    int bi = c & 1;
    if (c + 1 < NCHK) stage(c + 1, bi ^ 1);
    const short* pb = (const short*)&sbuf[bi][0];
    #pragma unroll
    for (int kb = 0; kb < 2; ++kb){
      int off = c*64 + kb*32;       // float index within row (+ rq*8 in ptr)
      float4 e0 = *(const float4*)(Ep + off);
      float4 e1 = *(const float4*)(Ep + off + 4);
      bf16x8 af[2];
      #pragma unroll
      for (int u = 0; u < 2; ++u){
        const float* fr = (u == 0) ? (Fp0 + off) : (Fp1 + off);
        float4 f0 = *(const float4*)fr;
        float4 f1 = *(const float4*)(fr + 4);
        float s0 = rcp_f(fmaf(e0.x, f0.x, 1.0f));
        float s1 = rcp_f(fmaf(e0.y, f0.y, 1.0f));
        float s2 = rcp_f(fmaf(e0.z, f0.z, 1.0f));
        float s3 = rcp_f(fmaf(e0.w, f0.w, 1.0f));
        float s4 = rcp_f(fmaf(e1.x, f1.x, 1.0f));
        float s5 = rcp_f(fmaf(e1.y, f1.y, 1.0f));
        float s6 = rcp_f(fmaf(e1.z, f1.z, 1.0f));
        float s7 = rcp_f(fmaf(e1.w, f1.w, 1.0f));
        union { unsigned u4[4]; bf16x8 v; } a;
        a.u4[0] = pkbf(s0, s1); a.u4[1] = pkbf(s2, s3);
        a.u4[2] = pkbf(s4, s5); a.u4[3] = pkbf(s6, s7);
        af[u] = a.v;
      }
      #pragma unroll
      for (int nt = 0; nt < 7; ++nt){
        bf16x8 pf = *(const bf16x8*)(pb + (kb*7 + nt)*512 + lane*8);
        acc[0][nt] = __builtin_amdgcn_mfma_f32_16x16x32_bf16(af[0], pf, acc[0][nt], 0, 0, 0);
        acc[1][nt] = __builtin_amdgcn_mfma_f32_16x16x32_bf16(af[1], pf, acc[1][nt], 0, 0, 0);
      }
    }
    __syncthreads();
  }

  // D layout: col=lm -> label, row=rq*4+reg -> j
  #pragma unroll
  for (int u = 0; u < 2; ++u){
    int i = ibase + wave*2 + u;
    if (i >= nn) continue;
    size_t dbase = (size_t)i * nn * LD;
    #pragma unroll
    for (int reg = 0; reg < 4; ++reg){
      int j = jbase + rq*4 + reg;
      if (j >= nn) continue;
      float* op = out + dbase + (size_t)j*LD + lm;
      #pragma unroll
      for (int nt = 0; nt < 7; ++nt) op[nt*16] = acc[u][nt][reg];
    }
  }
}

extern "C" void kernel_launch(void* const* d_in, const int* in_sizes, int n_in,
                              void* d_out, int out_size, void* d_ws, size_t ws_size,
                              hipStream_t stream){
  const float* x  = (const float*)d_in[0];
  const float* W  = (const float*)d_in[1];
  const float* b  = (const float*)d_in[2];
  const float* P  = (const float*)d_in[3];
  const float* ob = (const float*)d_in[4];
  int ntok = in_sizes[0] / RD;   // 400
  int nn = ntok - 1;             // 399

  char* ws = (char*)d_ws;
  size_t o_fpb = 0;
  size_t o_Wb  = o_fpb + (size_t)ntok*RD*2;
  size_t o_Pt2 = o_Wb  + (size_t)RD*RD*2;
  size_t o_E   = o_Pt2 + (size_t)LD*RD*2;
  size_t o_F   = o_E   + (size_t)ntok*RD*4;
  size_t o_SB  = o_F   + (size_t)ntok*RD*4;
  short* fpb = (short*)(ws + o_fpb);
  short* Wb  = (short*)(ws + o_Wb);
  short* Pt2 = (short*)(ws + o_Pt2);
  float* E   = (float*)(ws + o_E);
  float* F   = (float*)(ws + o_F);
  float* SB  = (float*)(ws + o_SB);

  fence_prep<<<NB_CONV + LD, 256, 0, stream>>>(x, W, P, ob, fpb, Wb, Pt2, SB, ntok);

  int mtiles = (ntok + 15) / 16;       // 25
  fence_y<<<mtiles*16, 256, 0, stream>>>(fpb, Wb, b, E, F, ntok);

  int njt = (nn + 15) / 16;            // 25
  int nit = (nn + 7) / 8;              // 50
  fence_out<<<nit*njt, 256, 0, stream>>>(E, F, Pt2, SB, (float*)d_out, nn, njt);
}

// Round 5
// 170.808 us; speedup vs baseline: 1.3314x; 1.3314x over previous
//
#include <hip/hip_runtime.h>
#include <hip/hip_bf16.h>
#include <stdint.h>

typedef __attribute__((ext_vector_type(8))) short bf16x8;  // 8 bf16 (4 VGPRs)
typedef __attribute__((ext_vector_type(4))) float f32x4;   // 4 f32 acc

#define RD 1024
#define LD 112
#define SCALE_C 2.8853900817779268f   // 2/ln2: tanh(z) = 1 - 2/(1+2^(C*z))
#define CHK 64                        // k per LDS chunk in fence_out
#define NCHK (RD/CHK)                 // 16 chunks
#define NB_PT2 448                    // 448*256 = LD*RD elements
// flat LDS chunk buffer layout (bytes): Pt2 14 KB | E 4 KB | F 2 KB = 20 KB
#define OFF_E 14336
#define OFF_F 18432

static __device__ __forceinline__ unsigned pkbf(float lo, float hi){
  return __builtin_amdgcn_perm(__builtin_bit_cast(unsigned, hi),
                               __builtin_bit_cast(unsigned, lo), 0x07060302u);
}
static __device__ __forceinline__ float exp2_f(float t){
#if __has_builtin(__builtin_amdgcn_exp2f)
  return __builtin_amdgcn_exp2f(t);
#else
  return exp2f(t);
#endif
}
static __device__ __forceinline__ float rcp_f(float t){
#if __has_builtin(__builtin_amdgcn_rcpf)
  return __builtin_amdgcn_rcpf(t);
#else
  return 1.0f / t;
#endif
}
static __device__ __forceinline__ short f2bf_rn(float f){
  unsigned u = __builtin_bit_cast(unsigned, f);
  return (short)((u + 0x7fffu + ((u >> 16) & 1u)) >> 16);
}
// two round-to-nearest bf16 packed into one dword (matches f2bf_rn exactly)
static __device__ __forceinline__ unsigned pk2bf(float lo, float hi){
  return (unsigned)(unsigned short)f2bf_rn(lo) |
         ((unsigned)(unsigned short)f2bf_rn(hi) << 16);
}
typedef const __attribute__((address_space(1))) unsigned int* gas1;
typedef __attribute__((address_space(3))) unsigned int* las3;
static __device__ __forceinline__ void g2lds16(const void* g, void* l){
  __builtin_amdgcn_global_load_lds((gas1)g, (las3)l, 16, 0, 0);
}

// ---- fence_py: fused prep + y (3 dispatches -> 2 total).
//      Blocks [0, nby): y = fp*W^T via bf16 MFMA with IN-REGISTER f32->bf16
//      conversion of x and W (identical f2bf_rn rounding as the old prep, so
//      results are bit-identical; removes the prep->y dependency and the
//      fpb/Wb intermediates entirely). Epilogue E=2^(C(y+b)), F=2^(-Cy).
//      Blocks [nby, nby+448): Pt2[l*RD+r] = bf16(-2*P[r,l]).
//      Blocks [nby+448, nby+448+112): SB[l] = sum_r P[r,l] + ob[l]. ----
__global__ __launch_bounds__(256, 4)
void fence_py(const float* __restrict__ x, const float* __restrict__ W,
              const float* __restrict__ b, const float* __restrict__ P,
              const float* __restrict__ ob, short* __restrict__ Pt2,
              float* __restrict__ SB, float* __restrict__ E,
              float* __restrict__ F, int ntok, int nby){
  __shared__ float red[256];
  int blk = blockIdx.x, t = threadIdx.x;
  if (blk < nby){
    int wid  = blk*4 + (t >> 6);
    int lane = t & 63;
    int mt = wid >> 6;          // 0..24
    int ng = wid & 63;          // 0..63
    int lm = lane & 15, rq = lane >> 4;
    int arow = mt*16 + lm;
    float asc = (arow < ntok - 1) ? 1.0f : 0.0f;   // fp row 399.. is zero
    if (arow > ntok - 1) arow = ntok - 1;
    int arow1 = (arow + 1 < ntok) ? (arow + 1) : arow;  // stay in-bounds
    const float* A0 = x + (size_t)arow*RD + rq*8;
    const float* A1 = x + (size_t)arow1*RD + rq*8;
    const float* Bw = W + (size_t)(ng*16 + lm)*RD + rq*8;
    f32x4 acc = {};
    #pragma unroll
    for (int kb = 0; kb < 32; ++kb){
      const float* ap = (kb < 16) ? A0 : A1;       // fp = [x[i,:512], -x[i+1,512:]]
      float sg = (kb < 16) ? asc : -asc;
      float4 v0 = *(const float4*)(ap + kb*32);
      float4 v1 = *(const float4*)(ap + kb*32 + 4);
      float4 w0 = *(const float4*)(Bw + kb*32);
      float4 w1 = *(const float4*)(Bw + kb*32 + 4);
      union { unsigned u4[4]; bf16x8 v; } a, w;
      a.u4[0] = pk2bf(sg*v0.x, sg*v0.y);
      a.u4[1] = pk2bf(sg*v0.z, sg*v0.w);
      a.u4[2] = pk2bf(sg*v1.x, sg*v1.y);
      a.u4[3] = pk2bf(sg*v1.z, sg*v1.w);
      w.u4[0] = pk2bf(w0.x, w0.y);
      w.u4[1] = pk2bf(w0.z, w0.w);
      w.u4[2] = pk2bf(w1.x, w1.y);
      w.u4[3] = pk2bf(w1.z, w1.w);
      acc = __builtin_amdgcn_mfma_f32_16x16x32_bf16(a.v, w.v, acc, 0, 0, 0);
    }
    int r = ng*16 + lm;
    float bv = b[r];
    #pragma unroll
    for (int reg = 0; reg < 4; ++reg){
      int tt = mt*16 + rq*4 + reg;
      if (tt < ntok){
        float y = acc[reg];
        E[(size_t)tt*RD + r] = exp2_f(SCALE_C * (y + bv));
        F[(size_t)tt*RD + r] = exp2_f(-SCALE_C * y);
      }
    }
  } else if (blk < nby + NB_PT2){
    int id = (blk - nby)*256 + t;     // < LD*RD by exact sizing
    int l = id >> 10, rr = id & (RD - 1);
    Pt2[id] = f2bf_rn(-2.0f * P[rr*LD + l]);
  } else {
    int l = blk - nby - NB_PT2;       // 0..LD-1
    float s = 0.0f;
    for (int r = t; r < RD; r += 256) s += P[r*LD + l];
    red[t] = s; __syncthreads();
    for (int st = 128; st > 0; st >>= 1){
      if (t < st) red[t] += red[t + st];
      __syncthreads();
    }
    if (t == 0) SB[l] = red[0] + ob[l];
  }
}

// ---- fence_out: EXACT R0 structure (72.3 us measured; R1-R4 proved every
//      perturbation regresses). out[i,j,l] = SB[l] - 2*sum_r sigma*P[r,l],
//      sigma=1/(1+E_j F_i). Block = 8i x 16j, 4 waves x 2 i-rows. Pt2/E/F
//      staged per 64-k chunk via global_load_lds (double-buffered 2x20 KB).
//      E chunk stored XOR-swizzled at float4 granularity (slot s of row r
//      holds global float4 s^r) so the 16-row-stride reads are
//      bank-conflict-free without padding. ----
__global__ __launch_bounds__(256, 4)
void fence_out(const float* __restrict__ E, const float* __restrict__ F,
               const short* __restrict__ Pt2, const float* __restrict__ SB,
               float* __restrict__ out, int nn, int njt){
  __shared__ __align__(16) char sbuf[2][20480];
  int wave = threadIdx.x >> 6, lane = threadIdx.x & 63;
  int lm = lane & 15, rq = lane >> 4;
  int it = blockIdx.x / njt, jt = blockIdx.x - it*njt;
  int ibase = it*8, jbase = jt*16;

  // per-wave stage descriptors: 5 x 1KB blocks each (20 total), precomputed
  const char* gp[5]; int lof[5]; int stp[5];
  #pragma unroll
  for (int s = 0; s < 5; ++s){
    int q = wave + s*4;
    if (q < 14){                       // Pt2: 14 blocks of (7 labels-of-16 x 2 kb)
      int kb = q / 7, g = q - kb*7;
      gp[s]  = (const char*)(Pt2 + (size_t)(g*16 + lm)*RD + kb*32 + rq*8);
      stp[s] = CHK*2;
      lof[s] = q*1024;
    } else if (q < 18){                // E: 4 blocks of 4 j-rows, XOR-swizzled src
      int ee = q - 14;
      int row = ee*4 + rq;             // 0..15
      int jr = jbase + row; if (jr > nn - 1) jr = nn - 1;
      int cb = lm ^ row;               // swizzle: slot lm holds float4 (lm^row)
      gp[s]  = (const char*)(E + (size_t)jr*RD + cb*4);
      stp[s] = CHK*4;
      lof[s] = OFF_E + ee*1024;
    } else {                           // F: 2 blocks of 4 i-rows, linear
      int ff = q - 18;
      int row = ff*4 + rq;             // 0..7
      int ir = ibase + row; if (ir > nn - 1) ir = nn - 1;
      gp[s]  = (const char*)(F + (size_t)ir*RD + lm*4);
      stp[s] = CHK*4;
      lof[s] = OFF_F + ff*1024;
    }
  }
  auto stage = [&](int c, int bi){
    #pragma unroll
    for (int s = 0; s < 5; ++s)
      g2lds16(gp[s] + (size_t)c*stp[s], &sbuf[bi][lof[s]]);
  };

  stage(0, 0);

  f32x4 acc[2][7];
  #pragma unroll
  for (int nt = 0; nt < 7; ++nt){
    float sv = SB[nt*16 + lm];
    acc[0][nt] = (f32x4){sv, sv, sv, sv};
    acc[1][nt] = (f32x4){sv, sv, sv, sv};
  }
  __syncthreads();

  for (int c = 0; c < NCHK; ++c){
    int bi = c & 1;
    if (c + 1 < NCHK) stage(c + 1, bi ^ 1);
    const short* pb = (const short*)&sbuf[bi][0];
    const float* eb = (const float*)&sbuf[bi][OFF_E];
    const float* fb = (const float*)&sbuf[bi][OFF_F];
    #pragma unroll
    for (int kb = 0; kb < 2; ++kb){
      int ko = kb*32 + rq*8;
      int cb0 = kb*8 + rq*2;
      float4 e0 = *(const float4*)(eb + lm*64 + ((cb0 ^ lm) * 4));
      float4 e1 = *(const float4*)(eb + lm*64 + (((cb0 + 1) ^ lm) * 4));
      bf16x8 af[2];
      #pragma unroll
      for (int u = 0; u < 2; ++u){
        const float* fr = fb + (wave*2 + u)*64 + ko;   // wave-uniform: broadcast
        float4 f0 = *(const float4*)fr;
        float4 f1 = *(const float4*)(fr + 4);
        float s0 = rcp_f(fmaf(e0.x, f0.x, 1.0f));
        float s1 = rcp_f(fmaf(e0.y, f0.y, 1.0f));
        float s2 = rcp_f(fmaf(e0.z, f0.z, 1.0f));
        float s3 = rcp_f(fmaf(e0.w, f0.w, 1.0f));
        float s4 = rcp_f(fmaf(e1.x, f1.x, 1.0f));
        float s5 = rcp_f(fmaf(e1.y, f1.y, 1.0f));
        float s6 = rcp_f(fmaf(e1.z, f1.z, 1.0f));
        float s7 = rcp_f(fmaf(e1.w, f1.w, 1.0f));
        union { unsigned u4[4]; bf16x8 v; } a;
        a.u4[0] = pkbf(s0, s1); a.u4[1] = pkbf(s2, s3);
        a.u4[2] = pkbf(s4, s5); a.u4[3] = pkbf(s6, s7);
        af[u] = a.v;
      }
      #pragma unroll
      for (int nt = 0; nt < 7; ++nt){
        bf16x8 pf = *(const bf16x8*)(pb + (kb*7 + nt)*512 + lane*8);
        acc[0][nt] = __builtin_amdgcn_mfma_f32_16x16x32_bf16(af[0], pf, acc[0][nt], 0, 0, 0);
        acc[1][nt] = __builtin_amdgcn_mfma_f32_16x16x32_bf16(af[1], pf, acc[1][nt], 0, 0, 0);
      }
    }
    __syncthreads();
  }

  // D layout: col=lm -> label, row=rq*4+reg -> j
  #pragma unroll
  for (int u = 0; u < 2; ++u){
    int i = ibase + wave*2 + u;
    if (i >= nn) continue;
    size_t dbase = (size_t)i * nn * LD;
    #pragma unroll
    for (int reg = 0; reg < 4; ++reg){
      int j = jbase + rq*4 + reg;
      if (j >= nn) continue;
      float* op = out + dbase + (size_t)j*LD + lm;
      #pragma unroll
      for (int nt = 0; nt < 7; ++nt) op[nt*16] = acc[u][nt][reg];
    }
  }
}

extern "C" void kernel_launch(void* const* d_in, const int* in_sizes, int n_in,
                              void* d_out, int out_size, void* d_ws, size_t ws_size,
                              hipStream_t stream){
  const float* x  = (const float*)d_in[0];
  const float* W  = (const float*)d_in[1];
  const float* b  = (const float*)d_in[2];
  const float* P  = (const float*)d_in[3];
  const float* ob = (const float*)d_in[4];
  int ntok = in_sizes[0] / RD;   // 400
  int nn = ntok - 1;             // 399

  char* ws = (char*)d_ws;
  size_t o_Pt2 = 0;
  size_t o_E   = o_Pt2 + (size_t)LD*RD*2;
  size_t o_F   = o_E   + (size_t)ntok*RD*4;
  size_t o_SB  = o_F   + (size_t)ntok*RD*4;
  short* Pt2 = (short*)(ws + o_Pt2);
  float* E   = (float*)(ws + o_E);
  float* F   = (float*)(ws + o_F);
  float* SB  = (float*)(ws + o_SB);

  int mtiles = (ntok + 15) / 16;       // 25
  int nby = mtiles*16;                 // 400 y-blocks
  fence_py<<<nby + NB_PT2 + LD, 256, 0, stream>>>(x, W, b, P, ob, Pt2, SB, E, F, ntok, nby);

  int njt = (nn + 15) / 16;            // 25
  int nit = (nn + 7) / 8;              // 50
  fence_out<<<nit*njt, 256, 0, stream>>>(E, F, Pt2, SB, (float*)d_out, nn, njt);
}

// Round 6
// 161.285 us; speedup vs baseline: 1.4100x; 1.0590x over previous
//
#include <hip/hip_runtime.h>
#include <hip/hip_bf16.h>
#include <stdint.h>

typedef __attribute__((ext_vector_type(8))) short bf16x8;  // 8 bf16 (4 VGPRs)
typedef __attribute__((ext_vector_type(4))) float f32x4;   // 4 f32 acc

#define RD 1024
#define LD 112
#define SCALE_C 2.8853900817779268f   // 2/ln2: tanh(z) = 1 - 2/(1+2^(C*z))
#define CHK 64                        // k per LDS chunk in fence_out
#define NCHK (RD/CHK)                 // 16 chunks
#define NB_CONV 6144                  // (400*1024 + 1024*1024 + 112*1024)/256
// flat LDS chunk buffer layout (bytes): Pt2 14 KB | E 4 KB | F 2 KB = 20 KB
#define OFF_E 14336
#define OFF_F 18432

static __device__ __forceinline__ unsigned pkbf(float lo, float hi){
  return __builtin_amdgcn_perm(__builtin_bit_cast(unsigned, hi),
                               __builtin_bit_cast(unsigned, lo), 0x07060302u);
}
static __device__ __forceinline__ float exp2_f(float t){
#if __has_builtin(__builtin_amdgcn_exp2f)
  return __builtin_amdgcn_exp2f(t);
#else
  return exp2f(t);
#endif
}
static __device__ __forceinline__ float rcp_f(float t){
#if __has_builtin(__builtin_amdgcn_rcpf)
  return __builtin_amdgcn_rcpf(t);
#else
  return 1.0f / t;
#endif
}
static __device__ __forceinline__ short f2bf_rn(float f){
  unsigned u = __builtin_bit_cast(unsigned, f);
  return (short)((u + 0x7fffu + ((u >> 16) & 1u)) >> 16);
}
typedef const __attribute__((address_space(1))) unsigned int* gas1;
typedef __attribute__((address_space(3))) unsigned int* las3;
static __device__ __forceinline__ void g2lds16(const void* g, void* l){
  __builtin_amdgcn_global_load_lds((gas1)g, (las3)l, 16, 0, 0);
}

// ---- fused prep: bf16 conversions + SB[l] = sum_r P[r][l] + out_bias[l] ----
// (R0 version restored: R5 proved in-kernel redundant W conversion in the y
// kernel costs more than this one-pass prep; remainder time is harness-fixed.)
__global__ void fence_prep(const float* __restrict__ x, const float* __restrict__ W,
                           const float* __restrict__ P, const float* __restrict__ ob,
                           short* __restrict__ fpb, short* __restrict__ Wb,
                           short* __restrict__ Pt2, float* __restrict__ SB, int ntok){
  __shared__ float red[256];
  int blk = blockIdx.x, t = threadIdx.x;
  if (blk < NB_CONV){
    int id = blk*256 + t;
    int nfp = ntok * RD;
    if (id < nfp){
      int tok = id >> 10, d = id & (RD - 1);
      float v = 0.0f;
      if (tok < ntok - 1) v = (d < RD/2) ? x[tok*RD + d] : -x[(tok+1)*RD + d];
      fpb[id] = f2bf_rn(v);
    } else if (id < nfp + RD*RD){
      int p = id - nfp;
      Wb[p] = f2bf_rn(W[p]);
    } else {
      int p = id - nfp - RD*RD;   // < LD*RD by exact grid sizing
      int l = p >> 10, r = p & (RD - 1);
      Pt2[p] = f2bf_rn(-2.0f * P[r*LD + l]);
    }
  } else {
    int l = blk - NB_CONV;        // 0..LD-1
    float s = 0.0f;
    for (int r = t; r < RD; r += 256) s += P[r*LD + l];
    red[t] = s; __syncthreads();
    for (int st = 128; st > 0; st >>= 1){
      if (t < st) red[t] += red[t + st];
      __syncthreads();
    }
    if (t == 0) SB[l] = red[0] + ob[l];
  }
}

// ---- fence_y: y = fp*W^T (bf16 MFMA); epilogue E=2^(C(y+b)), F=2^(-Cy) ----
__global__ __launch_bounds__(256, 4)
void fence_y(const short* __restrict__ fpb, const short* __restrict__ Wb,
             const float* __restrict__ b, float* __restrict__ E,
             float* __restrict__ F, int ntok){
  int wid  = blockIdx.x * 4 + (threadIdx.x >> 6);
  int lane = threadIdx.x & 63;
  int mt = wid >> 6;          // 0..24
  int ng = wid & 63;          // 0..63
  int lm = lane & 15, rq = lane >> 4;
  int arow = mt*16 + lm; if (arow > ntok - 1) arow = ntok - 1;
  const short* Ap = fpb + (size_t)arow*RD + rq*8;
  const short* Bp = Wb + (size_t)(ng*16 + lm)*RD + rq*8;
  f32x4 acc = {};
  #pragma unroll
  for (int kb = 0; kb < 32; ++kb){
    bf16x8 a = *(const bf16x8*)(Ap + kb*32);
    bf16x8 w = *(const bf16x8*)(Bp + kb*32);
    acc = __builtin_amdgcn_mfma_f32_16x16x32_bf16(a, w, acc, 0, 0, 0);
  }
  int r = ng*16 + lm;
  float bv = b[r];
  #pragma unroll
  for (int reg = 0; reg < 4; ++reg){
    int t = mt*16 + rq*4 + reg;
    if (t < ntok){
      float y = acc[reg];
      E[(size_t)t*RD + r] = exp2_f(SCALE_C * (y + bv));
      F[(size_t)t*RD + r] = exp2_f(-SCALE_C * y);
    }
  }
}

// ---- fence_out: out[i,j,l] = SB[l] - 2*sum_r sigma*P[r,l], sigma=1/(1+E_j F_i).
//      EXACT R0 structure (72.3 us; R1-R5 proved every resource-envelope or
//      load-ordering perturbation regresses: VGPR 60 + 56 AGPR acc and 40 KB
//      LDS sit exactly at the 16-waves/CU boundary, and E/F must stay LDS-
//      staged so ordinary VMEM loads never queue behind the global_load_lds
//      prefetch in the in-order vmcnt counter). R6 addition -- T5 only:
//      s_setprio(1) around the MFMA cluster. Blocks on a CU are independent
//      (not barrier-synced with each other, ~4.9 blocks/CU), so wave phase
//      diversity exists and priority keeps the matrix pipe fed during other
//      blocks' staging/VALU phases. Zero resource change.
//      E chunk stored XOR-swizzled at float4 granularity (slot s of row r
//      holds global float4 s^r) so 16-row-stride reads are conflict-free. ----
__global__ __launch_bounds__(256, 4)
void fence_out(const float* __restrict__ E, const float* __restrict__ F,
               const short* __restrict__ Pt2, const float* __restrict__ SB,
               float* __restrict__ out, int nn, int njt){
  __shared__ __align__(16) char sbuf[2][20480];
  int wave = threadIdx.x >> 6, lane = threadIdx.x & 63;
  int lm = lane & 15, rq = lane >> 4;
  int it = blockIdx.x / njt, jt = blockIdx.x - it*njt;
  int ibase = it*8, jbase = jt*16;

  // per-wave stage descriptors: 5 x 1KB blocks each (20 total), precomputed
  const char* gp[5]; int lof[5]; int stp[5];
  #pragma unroll
  for (int s = 0; s < 5; ++s){
    int q = wave + s*4;
    if (q < 14){                       // Pt2: 14 blocks of (7 labels-of-16 x 2 kb)
      int kb = q / 7, g = q - kb*7;
      gp[s]  = (const char*)(Pt2 + (size_t)(g*16 + lm)*RD + kb*32 + rq*8);
      stp[s] = CHK*2;
      lof[s] = q*1024;
    } else if (q < 18){                // E: 4 blocks of 4 j-rows, XOR-swizzled src
      int ee = q - 14;
      int row = ee*4 + rq;             // 0..15
      int jr = jbase + row; if (jr > nn - 1) jr = nn - 1;
      int cb = lm ^ row;               // swizzle: slot lm holds float4 (lm^row)
      gp[s]  = (const char*)(E + (size_t)jr*RD + cb*4);
      stp[s] = CHK*4;
      lof[s] = OFF_E + ee*1024;
    } else {                           // F: 2 blocks of 4 i-rows, linear
      int ff = q - 18;
      int row = ff*4 + rq;             // 0..7
      int ir = ibase + row; if (ir > nn - 1) ir = nn - 1;
      gp[s]  = (const char*)(F + (size_t)ir*RD + lm*4);
      stp[s] = CHK*4;
      lof[s] = OFF_F + ff*1024;
    }
  }
  auto stage = [&](int c, int bi){
    #pragma unroll
    for (int s = 0; s < 5; ++s)
      g2lds16(gp[s] + (size_t)c*stp[s], &sbuf[bi][lof[s]]);
  };

  stage(0, 0);

  f32x4 acc[2][7];
  #pragma unroll
  for (int nt = 0; nt < 7; ++nt){
    float sv = SB[nt*16 + lm];
    acc[0][nt] = (f32x4){sv, sv, sv, sv};
    acc[1][nt] = (f32x4){sv, sv, sv, sv};
  }
  __syncthreads();

  for (int c = 0; c < NCHK; ++c){
    int bi = c & 1;
    if (c + 1 < NCHK) stage(c + 1, bi ^ 1);
    const short* pb = (const short*)&sbuf[bi][0];
    const float* eb = (const float*)&sbuf[bi][OFF_E];
    const float* fb = (const float*)&sbuf[bi][OFF_F];
    #pragma unroll
    for (int kb = 0; kb < 2; ++kb){
      int ko = kb*32 + rq*8;
      int cb0 = kb*8 + rq*2;
      float4 e0 = *(const float4*)(eb + lm*64 + ((cb0 ^ lm) * 4));
      float4 e1 = *(const float4*)(eb + lm*64 + (((cb0 + 1) ^ lm) * 4));
      bf16x8 af[2];
      #pragma unroll
      for (int u = 0; u < 2; ++u){
        const float* fr = fb + (wave*2 + u)*64 + ko;   // wave-uniform: broadcast
        float4 f0 = *(const float4*)fr;
        float4 f1 = *(const float4*)(fr + 4);
        float s0 = rcp_f(fmaf(e0.x, f0.x, 1.0f));
        float s1 = rcp_f(fmaf(e0.y, f0.y, 1.0f));
        float s2 = rcp_f(fmaf(e0.z, f0.z, 1.0f));
        float s3 = rcp_f(fmaf(e0.w, f0.w, 1.0f));
        float s4 = rcp_f(fmaf(e1.x, f1.x, 1.0f));
        float s5 = rcp_f(fmaf(e1.y, f1.y, 1.0f));
        float s6 = rcp_f(fmaf(e1.z, f1.z, 1.0f));
        float s7 = rcp_f(fmaf(e1.w, f1.w, 1.0f));
        union { unsigned u4[4]; bf16x8 v; } a;
        a.u4[0] = pkbf(s0, s1); a.u4[1] = pkbf(s2, s3);
        a.u4[2] = pkbf(s4, s5); a.u4[3] = pkbf(s6, s7);
        af[u] = a.v;
      }
      __builtin_amdgcn_s_setprio(1);   // T5: favor this wave through the MFMA burst
      #pragma unroll
      for (int nt = 0; nt < 7; ++nt){
        bf16x8 pf = *(const bf16x8*)(pb + (kb*7 + nt)*512 + lane*8);
        acc[0][nt] = __builtin_amdgcn_mfma_f32_16x16x32_bf16(af[0], pf, acc[0][nt], 0, 0, 0);
        acc[1][nt] = __builtin_amdgcn_mfma_f32_16x16x32_bf16(af[1], pf, acc[1][nt], 0, 0, 0);
      }
      __builtin_amdgcn_s_setprio(0);
    }
    __syncthreads();
  }

  // D layout: col=lm -> label, row=rq*4+reg -> j
  #pragma unroll
  for (int u = 0; u < 2; ++u){
    int i = ibase + wave*2 + u;
    if (i >= nn) continue;
    size_t dbase = (size_t)i * nn * LD;
    #pragma unroll
    for (int reg = 0; reg < 4; ++reg){
      int j = jbase + rq*4 + reg;
      if (j >= nn) continue;
      float* op = out + dbase + (size_t)j*LD + lm;
      #pragma unroll
      for (int nt = 0; nt < 7; ++nt) op[nt*16] = acc[u][nt][reg];
    }
  }
}

extern "C" void kernel_launch(void* const* d_in, const int* in_sizes, int n_in,
                              void* d_out, int out_size, void* d_ws, size_t ws_size,
                              hipStream_t stream){
  const float* x  = (const float*)d_in[0];
  const float* W  = (const float*)d_in[1];
  const float* b  = (const float*)d_in[2];
  const float* P  = (const float*)d_in[3];
  const float* ob = (const float*)d_in[4];
  int ntok = in_sizes[0] / RD;   // 400
  int nn = ntok - 1;             // 399

  char* ws = (char*)d_ws;
  size_t o_fpb = 0;
  size_t o_Wb  = o_fpb + (size_t)ntok*RD*2;
  size_t o_Pt2 = o_Wb  + (size_t)RD*RD*2;
  size_t o_E   = o_Pt2 + (size_t)LD*RD*2;
  size_t o_F   = o_E   + (size_t)ntok*RD*4;
  size_t o_SB  = o_F   + (size_t)ntok*RD*4;
  short* fpb = (short*)(ws + o_fpb);
  short* Wb  = (short*)(ws + o_Wb);
  short* Pt2 = (short*)(ws + o_Pt2);
  float* E   = (float*)(ws + o_E);
  float* F   = (float*)(ws + o_F);
  float* SB  = (float*)(ws + o_SB);

  fence_prep<<<NB_CONV + LD, 256, 0, stream>>>(x, W, P, ob, fpb, Wb, Pt2, SB, ntok);

  int mtiles = (ntok + 15) / 16;       // 25
  fence_y<<<mtiles*16, 256, 0, stream>>>(fpb, Wb, b, E, F, ntok);

  int njt = (nn + 15) / 16;            // 25
  int nit = (nn + 7) / 8;              // 50
  fence_out<<<nit*njt, 256, 0, stream>>>(E, F, Pt2, SB, (float*)d_out, nn, njt);
}

// Round 7
// 157.990 us; speedup vs baseline: 1.4394x; 1.0209x over previous
//
#include <hip/hip_runtime.h>
#include <hip/hip_bf16.h>
#include <stdint.h>

typedef __attribute__((ext_vector_type(8))) short bf16x8;  // 8 bf16 (4 VGPRs)
typedef __attribute__((ext_vector_type(4))) short s16x4;   // 4 bf16 (8B store)
typedef __attribute__((ext_vector_type(4))) float f32x4;   // 4 f32 acc

#define RD 1024
#define LD 112
#define SCALE_C 2.8853900817779268f   // 2/ln2: tanh(z) = 1 - 2/(1+2^(C*z))
#define CHK 64                        // k per LDS chunk in fence_out
#define NCHK (RD/CHK)                 // 16 chunks
#define NB_PT2 448                    // 448*256 = LD*RD elements
// flat LDS chunk buffer layout (bytes): Pt2 14 KB | E 4 KB | F 2 KB = 20 KB
#define OFF_E 14336
#define OFF_F 18432

static __device__ __forceinline__ unsigned pkbf(float lo, float hi){
  return __builtin_amdgcn_perm(__builtin_bit_cast(unsigned, hi),
                               __builtin_bit_cast(unsigned, lo), 0x07060302u);
}
static __device__ __forceinline__ float exp2_f(float t){
#if __has_builtin(__builtin_amdgcn_exp2f)
  return __builtin_amdgcn_exp2f(t);
#else
  return exp2f(t);
#endif
}
static __device__ __forceinline__ float rcp_f(float t){
#if __has_builtin(__builtin_amdgcn_rcpf)
  return __builtin_amdgcn_rcpf(t);
#else
  return 1.0f / t;
#endif
}
static __device__ __forceinline__ short f2bf_rn(float f){
  unsigned u = __builtin_bit_cast(unsigned, f);
  return (short)((u + 0x7fffu + ((u >> 16) & 1u)) >> 16);
}
typedef const __attribute__((address_space(1))) unsigned int* gas1;
typedef __attribute__((address_space(3))) unsigned int* las3;
static __device__ __forceinline__ void g2lds16(const void* g, void* l){
  __builtin_amdgcn_global_load_lds((gas1)g, (las3)l, 16, 0, 0);
}

// ---- fence_prep: fpb/Wb bf16 conversion only, float4-vectorized (4 elems/
//      thread, 6256 -> 1424 blocks; prep was scalar-load + launch bound).
//      Pt2/SB moved into fence_y's dispatch (they don't depend on prep). ----
__global__ __launch_bounds__(256)
void fence_prep(const float* __restrict__ x, const float* __restrict__ W,
                short* __restrict__ fpb, short* __restrict__ Wb, int ntok){
  int id4 = blockIdx.x*256 + threadIdx.x;
  int nfp4 = ntok * (RD/4);
  if (id4 < nfp4){
    int id = id4*4;
    int tok = id >> 10, d = id & (RD - 1);
    float4 v = {0.0f, 0.0f, 0.0f, 0.0f};
    if (tok < ntok - 1){
      if (d < RD/2) v = *(const float4*)(x + (size_t)tok*RD + d);
      else {
        float4 w = *(const float4*)(x + (size_t)(tok+1)*RD + d);
        v = (float4){-w.x, -w.y, -w.z, -w.w};
      }
    }
    s16x4 o = {f2bf_rn(v.x), f2bf_rn(v.y), f2bf_rn(v.z), f2bf_rn(v.w)};
    *(s16x4*)(fpb + id) = o;
  } else if (id4 < nfp4 + (RD*RD/4)){
    int p = (id4 - nfp4)*4;
    float4 w = *(const float4*)(W + p);
    s16x4 o = {f2bf_rn(w.x), f2bf_rn(w.y), f2bf_rn(w.z), f2bf_rn(w.w)};
    *(s16x4*)(Wb + p) = o;
  }
}

// ---- fence_y: blocks [0,nby): y = fp*W^T (bf16 MFMA); epilogue
//      E=2^(C(y+b)), F=2^(-Cy). Blocks [nby,nby+448): Pt2[l*RD+r] =
//      bf16(-2*P[r,l]). Blocks [nby+448,+112): SB[l] = sum_r P[r,l]+ob[l].
//      Pt2/SB depend only on P/ob, so they fill this dispatch's low-TLP
//      tail (y alone is 400 blocks = 1.6/CU) instead of serializing in
//      prep. ----
__global__ __launch_bounds__(256, 4)
void fence_y(const short* __restrict__ fpb, const short* __restrict__ Wb,
             const float* __restrict__ b, const float* __restrict__ P,
             const float* __restrict__ ob, short* __restrict__ Pt2,
             float* __restrict__ SB, float* __restrict__ E,
             float* __restrict__ F, int ntok, int nby){
  __shared__ float red[256];
  int blk = blockIdx.x, t = threadIdx.x;
  if (blk < nby){
    int wid  = blk*4 + (t >> 6);
    int lane = t & 63;
    int mt = wid >> 6;          // 0..24
    int ng = wid & 63;          // 0..63
    int lm = lane & 15, rq = lane >> 4;
    int arow = mt*16 + lm; if (arow > ntok - 1) arow = ntok - 1;
    const short* Ap = fpb + (size_t)arow*RD + rq*8;
    const short* Bp = Wb + (size_t)(ng*16 + lm)*RD + rq*8;
    f32x4 acc = {};
    #pragma unroll
    for (int kb = 0; kb < 32; ++kb){
      bf16x8 a = *(const bf16x8*)(Ap + kb*32);
      bf16x8 w = *(const bf16x8*)(Bp + kb*32);
      acc = __builtin_amdgcn_mfma_f32_16x16x32_bf16(a, w, acc, 0, 0, 0);
    }
    int r = ng*16 + lm;
    float bv = b[r];
    #pragma unroll
    for (int reg = 0; reg < 4; ++reg){
      int tt = mt*16 + rq*4 + reg;
      if (tt < ntok){
        float y = acc[reg];
        E[(size_t)tt*RD + r] = exp2_f(SCALE_C * (y + bv));
        F[(size_t)tt*RD + r] = exp2_f(-SCALE_C * y);
      }
    }
  } else if (blk < nby + NB_PT2){
    int id = (blk - nby)*256 + t;     // < LD*RD by exact sizing
    int l = id >> 10, rr = id & (RD - 1);
    Pt2[id] = f2bf_rn(-2.0f * P[rr*LD + l]);
  } else {
    int l = blk - nby - NB_PT2;       // 0..LD-1
    float s = 0.0f;
    for (int r = t; r < RD; r += 256) s += P[r*LD + l];
    red[t] = s; __syncthreads();
    for (int st = 128; st > 0; st >>= 1){
      if (t < st) red[t] += red[t + st];
      __syncthreads();
    }
    if (t == 0) SB[l] = red[0] + ob[l];
  }
}

// ---- fence_out: out[i,j,l] = SB[l] - 2*sum_r sigma*P[r,l], sigma=1/(1+E_j F_i).
//      BYTE-IDENTICAL to R6 (68.4 us measured; best known). R1-R5 proved
//      every resource-envelope or load-ordering perturbation regresses:
//      VGPR 60 + 56 AGPR acc and 40 KB LDS sit exactly at the occupancy
//      boundary, and E/F must stay LDS-staged so ordinary VMEM loads never
//      queue behind the global_load_lds prefetch in the in-order vmcnt
//      counter. T5 s_setprio(1) around the MFMA cluster: +5.4% verified
//      (blocks on a CU are independent -> wave phase diversity).
//      E chunk stored XOR-swizzled at float4 granularity (slot s of row r
//      holds global float4 s^r) so 16-row-stride reads are conflict-free. ----
__global__ __launch_bounds__(256, 4)
void fence_out(const float* __restrict__ E, const float* __restrict__ F,
               const short* __restrict__ Pt2, const float* __restrict__ SB,
               float* __restrict__ out, int nn, int njt){
  __shared__ __align__(16) char sbuf[2][20480];
  int wave = threadIdx.x >> 6, lane = threadIdx.x & 63;
  int lm = lane & 15, rq = lane >> 4;
  int it = blockIdx.x / njt, jt = blockIdx.x - it*njt;
  int ibase = it*8, jbase = jt*16;

  // per-wave stage descriptors: 5 x 1KB blocks each (20 total), precomputed
  const char* gp[5]; int lof[5]; int stp[5];
  #pragma unroll
  for (int s = 0; s < 5; ++s){
    int q = wave + s*4;
    if (q < 14){                       // Pt2: 14 blocks of (7 labels-of-16 x 2 kb)
      int kb = q / 7, g = q - kb*7;
      gp[s]  = (const char*)(Pt2 + (size_t)(g*16 + lm)*RD + kb*32 + rq*8);
      stp[s] = CHK*2;
      lof[s] = q*1024;
    } else if (q < 18){                // E: 4 blocks of 4 j-rows, XOR-swizzled src
      int ee = q - 14;
      int row = ee*4 + rq;             // 0..15
      int jr = jbase + row; if (jr > nn - 1) jr = nn - 1;
      int cb = lm ^ row;               // swizzle: slot lm holds float4 (lm^row)
      gp[s]  = (const char*)(E + (size_t)jr*RD + cb*4);
      stp[s] = CHK*4;
      lof[s] = OFF_E + ee*1024;
    } else {                           // F: 2 blocks of 4 i-rows, linear
      int ff = q - 18;
      int row = ff*4 + rq;             // 0..7
      int ir = ibase + row; if (ir > nn - 1) ir = nn - 1;
      gp[s]  = (const char*)(F + (size_t)ir*RD + lm*4);
      stp[s] = CHK*4;
      lof[s] = OFF_F + ff*1024;
    }
  }
  auto stage = [&](int c, int bi){
    #pragma unroll
    for (int s = 0; s < 5; ++s)
      g2lds16(gp[s] + (size_t)c*stp[s], &sbuf[bi][lof[s]]);
  };

  stage(0, 0);

  f32x4 acc[2][7];
  #pragma unroll
  for (int nt = 0; nt < 7; ++nt){
    float sv = SB[nt*16 + lm];
    acc[0][nt] = (f32x4){sv, sv, sv, sv};
    acc[1][nt] = (f32x4){sv, sv, sv, sv};
  }
  __syncthreads();

  for (int c = 0; c < NCHK; ++c){
    int bi = c & 1;
    if (c + 1 < NCHK) stage(c + 1, bi ^ 1);
    const short* pb = (const short*)&sbuf[bi][0];
    const float* eb = (const float*)&sbuf[bi][OFF_E];
    const float* fb = (const float*)&sbuf[bi][OFF_F];
    #pragma unroll
    for (int kb = 0; kb < 2; ++kb){
      int ko = kb*32 + rq*8;
      int cb0 = kb*8 + rq*2;
      float4 e0 = *(const float4*)(eb + lm*64 + ((cb0 ^ lm) * 4));
      float4 e1 = *(const float4*)(eb + lm*64 + (((cb0 + 1) ^ lm) * 4));
      bf16x8 af[2];
      #pragma unroll
      for (int u = 0; u < 2; ++u){
        const float* fr = fb + (wave*2 + u)*64 + ko;   // wave-uniform: broadcast
        float4 f0 = *(const float4*)fr;
        float4 f1 = *(const float4*)(fr + 4);
        float s0 = rcp_f(fmaf(e0.x, f0.x, 1.0f));
        float s1 = rcp_f(fmaf(e0.y, f0.y, 1.0f));
        float s2 = rcp_f(fmaf(e0.z, f0.z, 1.0f));
        float s3 = rcp_f(fmaf(e0.w, f0.w, 1.0f));
        float s4 = rcp_f(fmaf(e1.x, f1.x, 1.0f));
        float s5 = rcp_f(fmaf(e1.y, f1.y, 1.0f));
        float s6 = rcp_f(fmaf(e1.z, f1.z, 1.0f));
        float s7 = rcp_f(fmaf(e1.w, f1.w, 1.0f));
        union { unsigned u4[4]; bf16x8 v; } a;
        a.u4[0] = pkbf(s0, s1); a.u4[1] = pkbf(s2, s3);
        a.u4[2] = pkbf(s4, s5); a.u4[3] = pkbf(s6, s7);
        af[u] = a.v;
      }
      __builtin_amdgcn_s_setprio(1);   // T5: favor this wave through the MFMA burst
      #pragma unroll
      for (int nt = 0; nt < 7; ++nt){
        bf16x8 pf = *(const bf16x8*)(pb + (kb*7 + nt)*512 + lane*8);
        acc[0][nt] = __builtin_amdgcn_mfma_f32_16x16x32_bf16(af[0], pf, acc[0][nt], 0, 0, 0);
        acc[1][nt] = __builtin_amdgcn_mfma_f32_16x16x32_bf16(af[1], pf, acc[1][nt], 0, 0, 0);
      }
      __builtin_amdgcn_s_setprio(0);
    }
    __syncthreads();
  }

  // D layout: col=lm -> label, row=rq*4+reg -> j
  #pragma unroll
  for (int u = 0; u < 2; ++u){
    int i = ibase + wave*2 + u;
    if (i >= nn) continue;
    size_t dbase = (size_t)i * nn * LD;
    #pragma unroll
    for (int reg = 0; reg < 4; ++reg){
      int j = jbase + rq*4 + reg;
      if (j >= nn) continue;
      float* op = out + dbase + (size_t)j*LD + lm;
      #pragma unroll
      for (int nt = 0; nt < 7; ++nt) op[nt*16] = acc[u][nt][reg];
    }
  }
}

extern "C" void kernel_launch(void* const* d_in, const int* in_sizes, int n_in,
                              void* d_out, int out_size, void* d_ws, size_t ws_size,
                              hipStream_t stream){
  const float* x  = (const float*)d_in[0];
  const float* W  = (const float*)d_in[1];
  const float* b  = (const float*)d_in[2];
  const float* P  = (const float*)d_in[3];
  const float* ob = (const float*)d_in[4];
  int ntok = in_sizes[0] / RD;   // 400
  int nn = ntok - 1;             // 399

  char* ws = (char*)d_ws;
  size_t o_fpb = 0;
  size_t o_Wb  = o_fpb + (size_t)ntok*RD*2;
  size_t o_Pt2 = o_Wb  + (size_t)RD*RD*2;
  size_t o_E   = o_Pt2 + (size_t)LD*RD*2;
  size_t o_F   = o_E   + (size_t)ntok*RD*4;
  size_t o_SB  = o_F   + (size_t)ntok*RD*4;
  short* fpb = (short*)(ws + o_fpb);
  short* Wb  = (short*)(ws + o_Wb);
  short* Pt2 = (short*)(ws + o_Pt2);
  float* E   = (float*)(ws + o_E);
  float* F   = (float*)(ws + o_F);
  float* SB  = (float*)(ws + o_SB);

  int nfp4 = ntok*(RD/4);
  int nbp  = (nfp4 + (RD*RD/4) + 255)/256;   // 1424
  fence_prep<<<nbp, 256, 0, stream>>>(x, W, fpb, Wb, ntok);

  int mtiles = (ntok + 15) / 16;       // 25
  int nby = mtiles*16;                 // 400 y-blocks
  fence_y<<<nby + NB_PT2 + LD, 256, 0, stream>>>(fpb, Wb, b, P, ob, Pt2, SB, E, F, ntok, nby);

  int njt = (nn + 15) / 16;            // 25
  int nit = (nn + 7) / 8;              // 50
  fence_out<<<nit*njt, 256, 0, stream>>>(E, F, Pt2, SB, (float*)d_out, nn, njt);
}